// Round 10
// baseline (2268.091 us; speedup 1.0000x reference)
//
#include <hip/hip_runtime.h>
#include <stdint.h>
#include <stddef.h>

// Problem constants (from reference): B=8, L=8192, D=1024, M=L/4=2048.
// Setup guarantees exactly M true mask positions per row -> counts == M.
#define B_ 8
#define L_ 8192
#define D_ 1024
#define M_ 2048
#define S_ 128           // segments per row
#define G_ 16            // M_/S_  (segment length)
#define D4_ (D_/4)

typedef float f4 __attribute__((ext_vector_type(4)));

// ---------------- workspace layout (bytes) ----------------
#define OFF_POS    ((size_t)0)
#define OFF_DEC    (OFF_POS  + (size_t)B_*M_*4)
#define OFF_FLAG   (OFF_DEC  + (size_t)B_*M_*4)              // int flag[B][S]
#define OFF_CIN    (OFF_FLAG + (size_t)B_*S_*4)              // float cin[B][S][D]
#define OFF_A      (OFF_CIN  + (size_t)B_*S_*D_*4)           // fallback
#define OFF_EZ     (OFF_A    + (size_t)B_*S_*4)              // fallback
#define OFF_HINIT  (OFF_EZ   + (size_t)B_*S_*D_*4)           // fallback
#define WS_TOTAL   (OFF_HINIT + (size_t)B_*S_*D_*4)

// ---------------- kernel 1: per-row compaction + flag reset -----------------
// One block (1024 threads) per batch row. Block 0 also zeroes the lookback
// flags (must happen every call: harness does not re-poison ws between
// replays). Mask dtype (u8 bool vs int32) detected from the first 8 KiB.
__global__ __launch_bounds__(1024)
void compact_kernel(const void* __restrict__ mask_raw,
                    const float* __restrict__ prob,
                    int* __restrict__ pos,
                    float* __restrict__ dec,
                    int* __restrict__ flags) {
    const int b = blockIdx.x;
    const int t = threadIdx.x;

    if (b == 0) flags[t] = 0;            // B_*S_ == 1024 flags, one per thread

    __shared__ int u8flag;
    if (t == 0) u8flag = 0;
    __syncthreads();
    {
        const uint32_t* mu = (const uint32_t*)mask_raw;
        uint32_t w0 = mu[t * 2], w1 = mu[t * 2 + 1];
        if (w0 > 1u || w1 > 1u) atomicOr(&u8flag, 1);
    }
    __syncthreads();
    const bool u8 = (u8flag != 0);

    int mv[8];
    const int base_l = t * 8;
    if (u8) {
        const uint8_t* mrow = (const uint8_t*)mask_raw + (size_t)b * L_;
        #pragma unroll
        for (int j = 0; j < 8; j++) mv[j] = mrow[base_l + j] ? 1 : 0;
    } else {
        const int* mrow = (const int*)mask_raw + (size_t)b * L_;
        #pragma unroll
        for (int j = 0; j < 8; j++) mv[j] = mrow[base_l + j] ? 1 : 0;
    }
    int tsum = 0;
    #pragma unroll
    for (int j = 0; j < 8; j++) tsum += mv[j];

    const int lane = t & 63, wid = t >> 6;
    int v = tsum;
    #pragma unroll
    for (int off = 1; off < 64; off <<= 1) {
        int n = __shfl_up(v, off, 64);
        if (lane >= off) v += n;
    }
    __shared__ int wsum[16];
    __shared__ int woff[16];
    if (lane == 63) wsum[wid] = v;
    __syncthreads();
    if (t < 16) {
        int acc = 0;
        for (int w = 0; w < t; w++) acc += wsum[w];
        woff[t] = acc;
    }
    __syncthreads();
    int run = (v - tsum) + woff[wid];

    const float* prow = prob + (size_t)b * L_;
    #pragma unroll
    for (int j = 0; j < 8; j++) {
        const int l = base_l + j;
        if (mv[j]) {
            float d = 1.0f - prow[l];
            d = fminf(fmaxf(d, 0.0f), 1.0f);
            pos[(size_t)b * M_ + run] = l;
            dec[(size_t)b * M_ + run] = d;
            run += 1;
        }
    }
}

// ---------------- kernel 2: decoupled-lookback mega scan --------------------
// One block per (b, segment). Phase A: local zero-init scan of the segment's
// 16 x rows -> (hz_end, A). Phase B: wait for carry-in c via per-(b) flag
// chain, publish carry-out. Phase C: run-scatter detokenizer seeded with c
// (round-8 flat NT pipeline; x re-reads are L2-hot from phase A).
// s is decorrelated from the CU assignment via a per-b shift so every CU
// hosts blocks at different chain depths.
__global__ __launch_bounds__(256)
void mega_kernel(const f4* __restrict__ x4,
                 const f4* __restrict__ res4,
                 const int* __restrict__ pos,
                 const float* __restrict__ dec,
                 const float* __restrict__ state,
                 float* __restrict__ cin,
                 int* __restrict__ flags,
                 f4* __restrict__ out4,
                 float* __restrict__ newstate) {
    const int id = blockIdx.x;
    const int b  = id >> 7;              // S_ = 128
    const int r  = id & (S_ - 1);
    const int s  = (r + b * 37) & (S_ - 1);
    const int t  = threadIdx.x;

    __shared__ int   pl[G_ + 1];
    __shared__ float dl[G_];
    if (t < G_) {
        pl[t] = pos[(size_t)b * M_ + (size_t)s * G_ + t];
        dl[t] = dec[(size_t)b * M_ + (size_t)s * G_ + t];
    }
    if (t == 0) {
        pl[G_] = (s == S_ - 1) ? L_ : pos[(size_t)b * M_ + (size_t)(s + 1) * G_];
    }
    __syncthreads();

    const f4* xrow = x4 + (size_t)b * L_ * D4_;

    // ---- phase A: zero-init segment scan (independent of the chain) ----
    f4 hz = (f4)(0.0f);
    #pragma unroll
    for (int m = 0; m < G_; m++) {
        const float d = dl[m];
        hz = d * hz + (1.0f - d) * xrow[(size_t)pl[m] * D4_ + t];
    }
    float A = 1.0f;
    #pragma unroll
    for (int m = 0; m < G_; m++) A *= dl[m];

    // ---- phase B: carry chain ----
    f4 c;
    if (s == 0) {
        c = ((const f4*)state)[(size_t)b * D4_ + t];
    } else {
        if (t == 0) {
            while (__hip_atomic_load(&flags[b * S_ + s], __ATOMIC_ACQUIRE,
                                     __HIP_MEMORY_SCOPE_AGENT) == 0) {
                __builtin_amdgcn_s_sleep(1);
            }
        }
        __syncthreads();
        const float* cs = cin + ((size_t)b * S_ + s) * D_ + t * 4;
        c.x = __hip_atomic_load(cs + 0, __ATOMIC_RELAXED, __HIP_MEMORY_SCOPE_AGENT);
        c.y = __hip_atomic_load(cs + 1, __ATOMIC_RELAXED, __HIP_MEMORY_SCOPE_AGENT);
        c.z = __hip_atomic_load(cs + 2, __ATOMIC_RELAXED, __HIP_MEMORY_SCOPE_AGENT);
        c.w = __hip_atomic_load(cs + 3, __ATOMIC_RELAXED, __HIP_MEMORY_SCOPE_AGENT);
    }
    {
        const f4 cout = hz + A * c;
        if (s < S_ - 1) {
            float* cn = cin + ((size_t)b * S_ + s + 1) * D_ + t * 4;
            __hip_atomic_store(cn + 0, cout.x, __ATOMIC_RELAXED, __HIP_MEMORY_SCOPE_AGENT);
            __hip_atomic_store(cn + 1, cout.y, __ATOMIC_RELAXED, __HIP_MEMORY_SCOPE_AGENT);
            __hip_atomic_store(cn + 2, cout.z, __ATOMIC_RELAXED, __HIP_MEMORY_SCOPE_AGENT);
            __hip_atomic_store(cn + 3, cout.w, __ATOMIC_RELAXED, __HIP_MEMORY_SCOPE_AGENT);
            __syncthreads();             // all publishes issued & drained
            if (t == 0) {
                __threadfence();
                __hip_atomic_store(&flags[b * S_ + s + 1], 1, __ATOMIC_RELEASE,
                                   __HIP_MEMORY_SCOPE_AGENT);
            }
        } else {
            ((f4*)newstate)[(size_t)b * D4_ + t] = cout;  // counts == M guaranteed
        }
    }

    // ---- phase C: flat run-scatter detokenizer (round-8 body, h seeded c) --
    const f4* resrow = res4 + (size_t)b * L_ * D4_;
    f4*       outrow = out4 + (size_t)b * L_ * D4_;

    if (s == 0) {
        const int p0 = pl[0];
        for (int l0 = 0; l0 < p0; l0++) {
            f4 rr = __builtin_nontemporal_load(resrow + (size_t)l0 * D4_ + t);
            __builtin_nontemporal_store(rr, outrow + (size_t)l0 * D4_ + t);
        }
    }

    f4 h = c;
    int m = -1;
    int nextb = pl[0];
    f4 xn  = xrow[(size_t)pl[0] * D4_ + t];
    f4 xn2 = xrow[(size_t)pl[1] * D4_ + t];
    int l = pl[0];
    const int lend = pl[G_];

    #define ADV(K, HH)                                                    \
        if (l + (K) == nextb) {                                           \
            ++m;                                                          \
            const float d_ = dl[m];                                       \
            h = d_ * h + (1.0f - d_) * xn;                                \
            xn = xn2;                                                     \
            nextb = pl[m + 1];                                            \
            const int ni_ = (m + 2 <= G_ - 1) ? pl[m + 2] : pl[0];        \
            xn2 = xrow[(size_t)ni_ * D4_ + t];                            \
        }                                                                 \
        HH = h;

    f4 c0, c1, c2, c3;
    if (l + 4 <= lend) {
        c0 = __builtin_nontemporal_load(resrow + (size_t)(l + 0) * D4_ + t);
        c1 = __builtin_nontemporal_load(resrow + (size_t)(l + 1) * D4_ + t);
        c2 = __builtin_nontemporal_load(resrow + (size_t)(l + 2) * D4_ + t);
        c3 = __builtin_nontemporal_load(resrow + (size_t)(l + 3) * D4_ + t);
    }
    while (l + 8 <= lend) {
        f4 n0 = __builtin_nontemporal_load(resrow + (size_t)(l + 4) * D4_ + t);
        f4 n1 = __builtin_nontemporal_load(resrow + (size_t)(l + 5) * D4_ + t);
        f4 n2 = __builtin_nontemporal_load(resrow + (size_t)(l + 6) * D4_ + t);
        f4 n3 = __builtin_nontemporal_load(resrow + (size_t)(l + 7) * D4_ + t);
        f4 h0, h1, h2, h3;
        ADV(0, h0); ADV(1, h1); ADV(2, h2); ADV(3, h3);
        __builtin_nontemporal_store(c0 + h0, outrow + (size_t)(l + 0) * D4_ + t);
        __builtin_nontemporal_store(c1 + h1, outrow + (size_t)(l + 1) * D4_ + t);
        __builtin_nontemporal_store(c2 + h2, outrow + (size_t)(l + 2) * D4_ + t);
        __builtin_nontemporal_store(c3 + h3, outrow + (size_t)(l + 3) * D4_ + t);
        c0 = n0; c1 = n1; c2 = n2; c3 = n3;
        l += 4;
    }
    if (l + 4 <= lend) {
        f4 h0, h1, h2, h3;
        ADV(0, h0); ADV(1, h1); ADV(2, h2); ADV(3, h3);
        __builtin_nontemporal_store(c0 + h0, outrow + (size_t)(l + 0) * D4_ + t);
        __builtin_nontemporal_store(c1 + h1, outrow + (size_t)(l + 1) * D4_ + t);
        __builtin_nontemporal_store(c2 + h2, outrow + (size_t)(l + 2) * D4_ + t);
        __builtin_nontemporal_store(c3 + h3, outrow + (size_t)(l + 3) * D4_ + t);
        l += 4;
    }
    for (; l < lend; l++) {
        f4 hh;
        ADV(0, hh);
        f4 rr = __builtin_nontemporal_load(resrow + (size_t)l * D4_ + t);
        __builtin_nontemporal_store(rr + hh, outrow + (size_t)l * D4_ + t);
    }
    #undef ADV
}

// ============================================================================
// Fallback path (round-8 verified 4-kernel pipeline) if coop launch fails.
// ============================================================================
__global__ __launch_bounds__(256)
void segend_kernel(const f4* __restrict__ x4,
                   const int* __restrict__ pos,
                   const float* __restrict__ dec,
                   f4* __restrict__ ez4,
                   float* __restrict__ Aseg) {
    const int blk = blockIdx.x;
    const int b = blk / S_, s = blk % S_;
    const int t = threadIdx.x;
    __shared__ int   pl[G_];
    __shared__ float dl[G_];
    if (t < G_) {
        pl[t] = pos[(size_t)b * M_ + (size_t)s * G_ + t];
        dl[t] = dec[(size_t)b * M_ + (size_t)s * G_ + t];
    }
    __syncthreads();
    f4 h = (f4)(0.0f);
    #pragma unroll
    for (int m = 0; m < G_; m++) {
        const float d = dl[m];
        h = d * h + (1.0f - d) * x4[((size_t)b * L_ + pl[m]) * D4_ + t];
    }
    ez4[(size_t)blk * D4_ + t] = h;
    if (t == 0) {
        float p = 1.0f;
        #pragma unroll
        for (int m = 0; m < G_; m++) p *= dl[m];
        Aseg[blk] = p;
    }
}

__global__ __launch_bounds__(64)
void combine_kernel(const float* __restrict__ ez,
                    const float* __restrict__ Aseg,
                    const float* __restrict__ state,
                    float* __restrict__ hinit,
                    float* __restrict__ newstate) {
    const int b = blockIdx.x;
    const int ch = blockIdx.y * 64 + threadIdx.x;
    __shared__ float Al[S_];
    for (int i = threadIdx.x; i < S_; i += 64) Al[i] = Aseg[b * S_ + i];
    __syncthreads();
    float c = state[(size_t)b * D_ + ch];
    for (int s0 = 0; s0 < S_; s0 += 8) {
        float e[8];
        #pragma unroll
        for (int j = 0; j < 8; j++)
            e[j] = ez[((size_t)b * S_ + s0 + j) * D_ + ch];
        #pragma unroll
        for (int j = 0; j < 8; j++) {
            hinit[((size_t)b * S_ + s0 + j) * D_ + ch] = c;
            c = fmaf(Al[s0 + j], c, e[j]);
        }
    }
    newstate[(size_t)b * D_ + ch] = c;
}

__global__ __launch_bounds__(256)
void fused_kernel(const f4* __restrict__ x4,
                  const f4* __restrict__ res4,
                  const int* __restrict__ pos,
                  const float* __restrict__ dec,
                  const f4* __restrict__ hinit4,
                  f4* __restrict__ out4) {
    const int blk = blockIdx.x;
    const int b = blk / S_, s = blk % S_;
    const int t = threadIdx.x;
    __shared__ int   pl[G_ + 1];
    __shared__ float dl[G_];
    if (t < G_) {
        pl[t] = pos[(size_t)b * M_ + (size_t)s * G_ + t];
        dl[t] = dec[(size_t)b * M_ + (size_t)s * G_ + t];
    }
    if (t == 0) {
        pl[G_] = (s == S_ - 1) ? L_ : pos[(size_t)b * M_ + (size_t)(s + 1) * G_];
    }
    __syncthreads();
    const f4* xrow   = x4   + (size_t)b * L_ * D4_;
    const f4* resrow = res4 + (size_t)b * L_ * D4_;
    f4*       outrow = out4 + (size_t)b * L_ * D4_;
    if (s == 0) {
        const int p0 = pl[0];
        for (int l0 = 0; l0 < p0; l0++) {
            f4 rr = __builtin_nontemporal_load(resrow + (size_t)l0 * D4_ + t);
            __builtin_nontemporal_store(rr, outrow + (size_t)l0 * D4_ + t);
        }
    }
    f4 h = hinit4[(size_t)blk * D4_ + t];
    int m = -1;
    int nextb = pl[0];
    f4 xn  = xrow[(size_t)pl[0] * D4_ + t];
    f4 xn2 = xrow[(size_t)pl[1] * D4_ + t];
    int l = pl[0];
    const int lend = pl[G_];
    #define ADV(K, HH)                                                    \
        if (l + (K) == nextb) {                                           \
            ++m;                                                          \
            const float d_ = dl[m];                                       \
            h = d_ * h + (1.0f - d_) * xn;                                \
            xn = xn2;                                                     \
            nextb = pl[m + 1];                                            \
            const int ni_ = (m + 2 <= G_ - 1) ? pl[m + 2] : pl[0];        \
            xn2 = xrow[(size_t)ni_ * D4_ + t];                            \
        }                                                                 \
        HH = h;
    f4 c0, c1, c2, c3;
    if (l + 4 <= lend) {
        c0 = __builtin_nontemporal_load(resrow + (size_t)(l + 0) * D4_ + t);
        c1 = __builtin_nontemporal_load(resrow + (size_t)(l + 1) * D4_ + t);
        c2 = __builtin_nontemporal_load(resrow + (size_t)(l + 2) * D4_ + t);
        c3 = __builtin_nontemporal_load(resrow + (size_t)(l + 3) * D4_ + t);
    }
    while (l + 8 <= lend) {
        f4 n0 = __builtin_nontemporal_load(resrow + (size_t)(l + 4) * D4_ + t);
        f4 n1 = __builtin_nontemporal_load(resrow + (size_t)(l + 5) * D4_ + t);
        f4 n2 = __builtin_nontemporal_load(resrow + (size_t)(l + 6) * D4_ + t);
        f4 n3 = __builtin_nontemporal_load(resrow + (size_t)(l + 7) * D4_ + t);
        f4 h0, h1, h2, h3;
        ADV(0, h0); ADV(1, h1); ADV(2, h2); ADV(3, h3);
        __builtin_nontemporal_store(c0 + h0, outrow + (size_t)(l + 0) * D4_ + t);
        __builtin_nontemporal_store(c1 + h1, outrow + (size_t)(l + 1) * D4_ + t);
        __builtin_nontemporal_store(c2 + h2, outrow + (size_t)(l + 2) * D4_ + t);
        __builtin_nontemporal_store(c3 + h3, outrow + (size_t)(l + 3) * D4_ + t);
        c0 = n0; c1 = n1; c2 = n2; c3 = n3;
        l += 4;
    }
    if (l + 4 <= lend) {
        f4 h0, h1, h2, h3;
        ADV(0, h0); ADV(1, h1); ADV(2, h2); ADV(3, h3);
        __builtin_nontemporal_store(c0 + h0, outrow + (size_t)(l + 0) * D4_ + t);
        __builtin_nontemporal_store(c1 + h1, outrow + (size_t)(l + 1) * D4_ + t);
        __builtin_nontemporal_store(c2 + h2, outrow + (size_t)(l + 2) * D4_ + t);
        __builtin_nontemporal_store(c3 + h3, outrow + (size_t)(l + 3) * D4_ + t);
        l += 4;
    }
    for (; l < lend; l++) {
        f4 hh;
        ADV(0, hh);
        f4 rr = __builtin_nontemporal_load(resrow + (size_t)l * D4_ + t);
        __builtin_nontemporal_store(rr + hh, outrow + (size_t)l * D4_ + t);
    }
    #undef ADV
}

extern "C" void kernel_launch(void* const* d_in, const int* in_sizes, int n_in,
                              void* d_out, int out_size, void* d_ws, size_t ws_size,
                              hipStream_t stream) {
    const float* x        = (const float*)d_in[0];
    const float* residual = (const float*)d_in[1];
    const float* prob     = (const float*)d_in[2];
    const void*  mask     = d_in[3];
    const float* state    = (const float*)d_in[4];

    float* out       = (float*)d_out;                       // (B,L,D)
    float* new_state = out + (size_t)B_ * L_ * D_;          // (B,D)

    if (ws_size < WS_TOTAL) return;

    char* ws = (char*)d_ws;
    int*   pos   = (int*)  (ws + OFF_POS);
    float* dec   = (float*)(ws + OFF_DEC);
    int*   flags = (int*)  (ws + OFF_FLAG);
    float* cin   = (float*)(ws + OFF_CIN);
    float* Aseg  = (float*)(ws + OFF_A);
    float* ez    = (float*)(ws + OFF_EZ);
    float* hinit = (float*)(ws + OFF_HINIT);

    compact_kernel<<<B_, 1024, 0, stream>>>(mask, prob, pos, dec, flags);

    const f4* x4   = (const f4*)x;
    const f4* res4 = (const f4*)residual;
    f4*       out4 = (f4*)out;

    void* args[] = {
        (void*)&x4, (void*)&res4, (void*)&pos, (void*)&dec, (void*)&state,
        (void*)&cin, (void*)&flags, (void*)&out4, (void*)&new_state
    };
    hipError_t err = hipLaunchCooperativeKernel(
        (const void*)mega_kernel, dim3(B_ * S_), dim3(256), args, 0, stream);

    if (err != hipSuccess) {
        // fallback: round-8 verified pipeline
        segend_kernel<<<B_ * S_, 256, 0, stream>>>(x4, pos, dec, (f4*)ez, Aseg);
        combine_kernel<<<dim3(B_, 16), 64, 0, stream>>>(ez, Aseg, state, hinit, new_state);
        fused_kernel<<<B_ * S_, 256, 0, stream>>>(x4, res4, pos, dec, (const f4*)hinit, out4);
    }
}

// Round 11
// 139.985 us; speedup vs baseline: 16.2024x; 16.2024x over previous
//
#include <hip/hip_runtime.h>
#include <stdint.h>
#include <stddef.h>

// Problem constants (from reference): B=8, L=8192, D=1024, M=L/4=2048.
// Setup guarantees exactly M true mask positions per row -> counts == M.
#define B_ 8
#define L_ 8192
#define D_ 1024
#define M_ 2048
#define S_ 128           // segments per row (carry granularity)
#define G_ 16            // M_/S_  (segment length)
#define D4_ (D_/4)
#define TROWS_ 64        // rows per fused tile
#define NTILE_ (L_/TROWS_)   // 128 tiles per batch row

typedef float f4 __attribute__((ext_vector_type(4)));

// ---------------- workspace layout (bytes) ----------------
#define OFF_POS    ((size_t)0)
#define OFF_DEC    (OFF_POS  + (size_t)B_*M_*4)
#define OFF_A      (OFF_DEC  + (size_t)B_*M_*4)
#define OFF_CIT    (OFF_A    + (size_t)B_*S_*4)              // int ci_tile[B][NTILE]
#define OFF_EZ     (OFF_CIT  + (size_t)B_*NTILE_*4)
#define OFF_HINIT  (OFF_EZ   + (size_t)B_*S_*D_*4)
#define WS_TOTAL   (OFF_HINIT + (size_t)B_*S_*D_*4)

// ---------------- kernel 1: per-row compaction (prefix sum over mask) -------
// One block (1024 threads) per batch row; thread t owns l = 8t..8t+7.
// Also emits ci_tile[b][k] = ci[64k-1] (chunk index active entering tile k).
// Mask dtype (1-byte bool vs int32) detected in-block from the first 8 KiB.
__global__ __launch_bounds__(1024)
void compact_kernel(const void* __restrict__ mask_raw,
                    const float* __restrict__ prob,
                    int* __restrict__ pos,
                    float* __restrict__ dec,
                    int* __restrict__ ci_tile) {
    const int b = blockIdx.x;
    const int t = threadIdx.x;

    __shared__ int u8flag;
    if (t == 0) u8flag = 0;
    __syncthreads();
    {
        const uint32_t* mu = (const uint32_t*)mask_raw;
        uint32_t w0 = mu[t * 2], w1 = mu[t * 2 + 1];
        if (w0 > 1u || w1 > 1u) atomicOr(&u8flag, 1);
    }
    __syncthreads();
    const bool u8 = (u8flag != 0);

    int mv[8];
    const int base_l = t * 8;
    if (u8) {
        const uint8_t* mrow = (const uint8_t*)mask_raw + (size_t)b * L_;
        #pragma unroll
        for (int j = 0; j < 8; j++) mv[j] = mrow[base_l + j] ? 1 : 0;
    } else {
        const int* mrow = (const int*)mask_raw + (size_t)b * L_;
        #pragma unroll
        for (int j = 0; j < 8; j++) mv[j] = mrow[base_l + j] ? 1 : 0;
    }
    int tsum = 0;
    #pragma unroll
    for (int j = 0; j < 8; j++) tsum += mv[j];

    // block-wide exclusive scan of per-thread sums (wave64 x 16 waves)
    const int lane = t & 63, wid = t >> 6;
    int v = tsum;
    #pragma unroll
    for (int off = 1; off < 64; off <<= 1) {
        int n = __shfl_up(v, off, 64);
        if (lane >= off) v += n;
    }
    __shared__ int wsum[16];
    __shared__ int woff[16];
    if (lane == 63) wsum[wid] = v;
    __syncthreads();
    if (t < 16) {
        int acc = 0;
        for (int w = 0; w < t; w++) acc += wsum[w];
        woff[t] = acc;
    }
    __syncthreads();
    int run = (v - tsum) + woff[wid];   // exclusive prefix for this thread

    const float* prow = prob + (size_t)b * L_;
    #pragma unroll
    for (int j = 0; j < 8; j++) {
        const int l = base_l + j;
        if (mv[j]) {
            float d = 1.0f - prow[l];
            d = fminf(fmaxf(d, 0.0f), 1.0f);
            pos[(size_t)b * M_ + run] = l;
            dec[(size_t)b * M_ + run] = d;
            run += 1;
        }
    }
    // after l = 8t+7: run = #pos <= 8t+7. Tile k starts at l0=64k=8t+8 when
    // (t+1)%8==0 -> ci[l0-1] = run-1.
    if ((t & 7) == 7) {
        const int k = (t + 1) >> 3;
        if (k < NTILE_) ci_tile[b * NTILE_ + k] = run - 1;
    }
}

// ---------------- kernel 2: zero-init segment END values + decay products ---
__global__ __launch_bounds__(256)
void segend_kernel(const f4* __restrict__ x4,
                   const int* __restrict__ pos,
                   const float* __restrict__ dec,
                   f4* __restrict__ ez4,
                   float* __restrict__ Aseg) {
    const int blk = blockIdx.x;          // b*S_ + s
    const int b = blk / S_, s = blk % S_;
    const int t = threadIdx.x;
    __shared__ int   pl[G_];
    __shared__ float dl[G_];
    if (t < G_) {
        pl[t] = pos[(size_t)b * M_ + (size_t)s * G_ + t];
        dl[t] = dec[(size_t)b * M_ + (size_t)s * G_ + t];
    }
    __syncthreads();
    f4 h = (f4)(0.0f);
    #pragma unroll
    for (int m = 0; m < G_; m++) {
        const float d = dl[m];
        h = d * h + (1.0f - d) * x4[((size_t)b * L_ + pl[m]) * D4_ + t];
    }
    ez4[(size_t)blk * D4_ + t] = h;
    if (t == 0) {
        float p = 1.0f;
        #pragma unroll
        for (int m = 0; m < G_; m++) p *= dl[m];
        Aseg[blk] = p;
    }
}

// ---------------- kernel 3: carry propagation across segments + new_state ---
__global__ __launch_bounds__(64)
void combine_kernel(const float* __restrict__ ez,
                    const float* __restrict__ Aseg,
                    const float* __restrict__ state,
                    float* __restrict__ hinit,
                    float* __restrict__ newstate) {
    const int b = blockIdx.x;
    const int ch = blockIdx.y * 64 + threadIdx.x;   // scalar channel 0..1023
    __shared__ float Al[S_];
    for (int i = threadIdx.x; i < S_; i += 64) Al[i] = Aseg[b * S_ + i];
    __syncthreads();

    float c = state[(size_t)b * D_ + ch];
    for (int s0 = 0; s0 < S_; s0 += 8) {
        float e[8];
        #pragma unroll
        for (int j = 0; j < 8; j++)
            e[j] = ez[((size_t)b * S_ + s0 + j) * D_ + ch];
        #pragma unroll
        for (int j = 0; j < 8; j++) {
            hinit[((size_t)b * S_ + s0 + j) * D_ + ch] = c;
            c = fmaf(Al[s0 + j], c, e[j]);
        }
    }
    newstate[(size_t)b * D_ + ch] = c;   // counts == M guaranteed
}

// ---------------- kernel 4: EQUAL-TILE fused scan + scatter -----------------
// One block (256 threads) per (b, 64-row tile). Prologue reconstructs the scan
// state at the tile start (hinit[seg] + masked 16-step partial scan, all x
// loads issued together, L3-hot). Stream: fixed 64-row NT pipeline with a
// `live` mask handling the ci<0 prefix naturally.
__global__ __launch_bounds__(256)
void fused_kernel(const f4* __restrict__ x4,
                  const f4* __restrict__ res4,
                  const int* __restrict__ pos,
                  const float* __restrict__ dec,
                  const int* __restrict__ ci_tile,
                  const float* __restrict__ state,
                  const f4* __restrict__ hinit4,
                  f4* __restrict__ out4) {
    const int blk = blockIdx.x;          // b*NTILE_ + k
    const int b = blk >> 7;              // NTILE_ = 128
    const int k = blk & (NTILE_ - 1);
    const int t = threadIdx.x;
    const int l0 = k * TROWS_;

    const int m0 = (k == 0) ? -1 : ci_tile[b * NTILE_ + k];

    // boundary list for this tile: chunks m0+1 .. m0+TROWS_+1 (sentinel-padded)
    __shared__ int   pl[TROWS_ + 2];
    __shared__ float dl[TROWS_ + 2];
    if (t < TROWS_ + 2) {
        const int mm = m0 + 1 + t;
        if (mm < M_) {
            pl[t] = pos[(size_t)b * M_ + mm];
            dl[t] = dec[(size_t)b * M_ + mm];
        } else {
            pl[t] = L_;                  // sentinel: never matches a row
            dl[t] = 1.0f;
        }
    }
    __syncthreads();

    const f4* xrow = x4 + (size_t)b * L_ * D4_;

    // ---- prologue: h = ema[m0] (or state if m0 < 0), live mask ----
    f4 h;
    float live;
    if (m0 < 0) {
        h = ((const f4*)state)[(size_t)b * D4_ + t];
        live = 0.0f;
    } else {
        const int s0 = m0 >> 4;          // G_ = 16
        const int mbase = s0 << 4;
        h = hinit4[((size_t)b * S_ + s0) * D4_ + t];
        live = 1.0f;
        // fixed 16-step masked partial scan: steps with mj > m0 are no-ops
        #pragma unroll
        for (int j = 0; j < G_; j++) {
            const int mj = mbase + j;
            const float draw = dec[(size_t)b * M_ + mj];
            const float d = (mj <= m0) ? draw : 1.0f;
            const f4 xv = xrow[(size_t)pos[(size_t)b * M_ + mj] * D4_ + t];
            h = d * h + (1.0f - d) * xv;
        }
    }

    // ---- stream: 64 rows, NT pipeline, ADV at boundaries ----
    const f4* resrow = res4 + (size_t)b * L_ * D4_;
    f4*       outrow = out4 + (size_t)b * L_ * D4_;

    int mi = 0;
    int nextb = pl[0];
    int a0 = (pl[0] < L_) ? pl[0] : 0;
    int a1 = (pl[1] < L_) ? pl[1] : 0;
    f4 xn  = xrow[(size_t)a0 * D4_ + t];
    f4 xn2 = xrow[(size_t)a1 * D4_ + t];
    int l = l0;

    #define ADV(K, HH, LV)                                                \
        if (l + (K) == nextb) {                                           \
            const float d_ = dl[mi];                                      \
            h = d_ * h + (1.0f - d_) * xn;                                \
            live = 1.0f;                                                  \
            xn = xn2;                                                     \
            ++mi;                                                         \
            nextb = pl[mi];                                               \
            const int nr_ = (pl[mi + 1] < L_) ? pl[mi + 1] : 0;           \
            xn2 = xrow[(size_t)nr_ * D4_ + t];                            \
        }                                                                 \
        HH = h; LV = live;

    f4 c0, c1, c2, c3;
    c0 = __builtin_nontemporal_load(resrow + (size_t)(l + 0) * D4_ + t);
    c1 = __builtin_nontemporal_load(resrow + (size_t)(l + 1) * D4_ + t);
    c2 = __builtin_nontemporal_load(resrow + (size_t)(l + 2) * D4_ + t);
    c3 = __builtin_nontemporal_load(resrow + (size_t)(l + 3) * D4_ + t);
    for (int g = 0; g < (TROWS_ / 4) - 1; ++g) {
        f4 n0 = __builtin_nontemporal_load(resrow + (size_t)(l + 4) * D4_ + t);
        f4 n1 = __builtin_nontemporal_load(resrow + (size_t)(l + 5) * D4_ + t);
        f4 n2 = __builtin_nontemporal_load(resrow + (size_t)(l + 6) * D4_ + t);
        f4 n3 = __builtin_nontemporal_load(resrow + (size_t)(l + 7) * D4_ + t);
        f4 h0, h1, h2, h3;
        float v0, v1, v2, v3;
        ADV(0, h0, v0); ADV(1, h1, v1); ADV(2, h2, v2); ADV(3, h3, v3);
        __builtin_nontemporal_store(c0 + v0 * h0, outrow + (size_t)(l + 0) * D4_ + t);
        __builtin_nontemporal_store(c1 + v1 * h1, outrow + (size_t)(l + 1) * D4_ + t);
        __builtin_nontemporal_store(c2 + v2 * h2, outrow + (size_t)(l + 2) * D4_ + t);
        __builtin_nontemporal_store(c3 + v3 * h3, outrow + (size_t)(l + 3) * D4_ + t);
        c0 = n0; c1 = n1; c2 = n2; c3 = n3;
        l += 4;
    }
    {
        f4 h0, h1, h2, h3;
        float v0, v1, v2, v3;
        ADV(0, h0, v0); ADV(1, h1, v1); ADV(2, h2, v2); ADV(3, h3, v3);
        __builtin_nontemporal_store(c0 + v0 * h0, outrow + (size_t)(l + 0) * D4_ + t);
        __builtin_nontemporal_store(c1 + v1 * h1, outrow + (size_t)(l + 1) * D4_ + t);
        __builtin_nontemporal_store(c2 + v2 * h2, outrow + (size_t)(l + 2) * D4_ + t);
        __builtin_nontemporal_store(c3 + v3 * h3, outrow + (size_t)(l + 3) * D4_ + t);
    }
    #undef ADV
}

extern "C" void kernel_launch(void* const* d_in, const int* in_sizes, int n_in,
                              void* d_out, int out_size, void* d_ws, size_t ws_size,
                              hipStream_t stream) {
    const float* x        = (const float*)d_in[0];
    const float* residual = (const float*)d_in[1];
    const float* prob     = (const float*)d_in[2];
    const void*  mask     = d_in[3];
    const float* state    = (const float*)d_in[4];

    float* out       = (float*)d_out;                       // (B,L,D)
    float* new_state = out + (size_t)B_ * L_ * D_;          // (B,D)

    if (ws_size < WS_TOTAL) return;  // fail loudly (zeros) rather than corrupt

    char* ws = (char*)d_ws;
    int*   pos     = (int*)  (ws + OFF_POS);
    float* dec     = (float*)(ws + OFF_DEC);
    float* Aseg    = (float*)(ws + OFF_A);
    int*   ci_tile = (int*)  (ws + OFF_CIT);
    float* ez      = (float*)(ws + OFF_EZ);
    float* hinit   = (float*)(ws + OFF_HINIT);

    compact_kernel<<<B_, 1024, 0, stream>>>(mask, prob, pos, dec, ci_tile);

    segend_kernel<<<B_ * S_, 256, 0, stream>>>(
        (const f4*)x, pos, dec, (f4*)ez, Aseg);

    combine_kernel<<<dim3(B_, 16), 64, 0, stream>>>(
        ez, Aseg, state, hinit, new_state);

    fused_kernel<<<B_ * NTILE_, 256, 0, stream>>>(
        (const f4*)x, (const f4*)residual, pos, dec, ci_tile, state,
        (const f4*)hinit, (f4*)out);
}

// Round 12
// 134.919 us; speedup vs baseline: 16.8107x; 1.0375x over previous
//
#include <hip/hip_runtime.h>
#include <stdint.h>
#include <stddef.h>

// Problem constants (from reference): B=8, L=8192, D=1024, M=L/4=2048.
// Setup guarantees exactly M true mask positions per row -> counts == M.
#define B_ 8
#define L_ 8192
#define D_ 1024
#define M_ 2048
#define D4_ (D_/4)
#define TROWS_ 64            // rows per tile (carry + stream granularity)
#define NTILE_ (L_/TROWS_)   // 128 tiles per batch row

typedef float f4 __attribute__((ext_vector_type(4)));

// ---------------- workspace layout (bytes) ----------------
#define OFF_POS    ((size_t)0)
#define OFF_DEC    (OFF_POS  + (size_t)B_*M_*4)
#define OFF_A      (OFF_DEC  + (size_t)B_*M_*4)              // float A[B][NTILE]
#define OFF_CIT    (OFF_A    + (size_t)B_*NTILE_*4)          // int ci_tile[B][NTILE]
#define OFF_EZ     (OFF_CIT  + (size_t)B_*NTILE_*4)          // float ez[B][NTILE][D]
#define OFF_HINIT  (OFF_EZ   + (size_t)B_*NTILE_*D_*4)       // float hinit[B][NTILE][D]
#define WS_TOTAL   (OFF_HINIT + (size_t)B_*NTILE_*D_*4)

// ---------------- kernel 1: per-row compaction (prefix sum over mask) -------
// One block (1024 threads) per batch row; thread t owns l = 8t..8t+7.
// Also emits ci_tile[b][k] = ci[64k-1] (chunk index active entering tile k),
// k = 1..127 (k=0 is implicitly -1). Mask dtype (u8 bool vs int32) detected
// in-block from the first 8 KiB.
__global__ __launch_bounds__(1024)
void compact_kernel(const void* __restrict__ mask_raw,
                    const float* __restrict__ prob,
                    int* __restrict__ pos,
                    float* __restrict__ dec,
                    int* __restrict__ ci_tile) {
    const int b = blockIdx.x;
    const int t = threadIdx.x;

    __shared__ int u8flag;
    if (t == 0) u8flag = 0;
    __syncthreads();
    {
        const uint32_t* mu = (const uint32_t*)mask_raw;
        uint32_t w0 = mu[t * 2], w1 = mu[t * 2 + 1];
        if (w0 > 1u || w1 > 1u) atomicOr(&u8flag, 1);
    }
    __syncthreads();
    const bool u8 = (u8flag != 0);

    int mv[8];
    const int base_l = t * 8;
    if (u8) {
        const uint8_t* mrow = (const uint8_t*)mask_raw + (size_t)b * L_;
        #pragma unroll
        for (int j = 0; j < 8; j++) mv[j] = mrow[base_l + j] ? 1 : 0;
    } else {
        const int* mrow = (const int*)mask_raw + (size_t)b * L_;
        #pragma unroll
        for (int j = 0; j < 8; j++) mv[j] = mrow[base_l + j] ? 1 : 0;
    }
    int tsum = 0;
    #pragma unroll
    for (int j = 0; j < 8; j++) tsum += mv[j];

    // block-wide exclusive scan of per-thread sums (wave64 x 16 waves)
    const int lane = t & 63, wid = t >> 6;
    int v = tsum;
    #pragma unroll
    for (int off = 1; off < 64; off <<= 1) {
        int n = __shfl_up(v, off, 64);
        if (lane >= off) v += n;
    }
    __shared__ int wsum[16];
    __shared__ int woff[16];
    if (lane == 63) wsum[wid] = v;
    __syncthreads();
    if (t < 16) {
        int acc = 0;
        for (int w = 0; w < t; w++) acc += wsum[w];
        woff[t] = acc;
    }
    __syncthreads();
    int run = (v - tsum) + woff[wid];   // exclusive prefix for this thread

    const float* prow = prob + (size_t)b * L_;
    #pragma unroll
    for (int j = 0; j < 8; j++) {
        const int l = base_l + j;
        if (mv[j]) {
            float d = 1.0f - prow[l];
            d = fminf(fmaxf(d, 0.0f), 1.0f);
            pos[(size_t)b * M_ + run] = l;
            dec[(size_t)b * M_ + run] = d;
            run += 1;
        }
    }
    // after l = 8t+7: run = #chunks with pos <= 8t+7. Tile k starts at
    // l0 = 64k = 8(t+1) when (t+1)%8 == 0 -> ci_tile[k] = run-1.
    if ((t & 7) == 7) {
        const int k = (t + 1) >> 3;
        if (k < NTILE_) ci_tile[b * NTILE_ + k] = run - 1;
    }
}

// ---------------- kernel 2: per-TILE zero-init scan end + decay product -----
// One block per (b, tile k): scans the tile's chunk range
// [mlo, mhi] = [ci_tile[k]+1, ci_tile[k+1]] (<= 64 chunks, since a row holds
// at most one chunk). Gathers batched 8-wide so loads pipeline.
__global__ __launch_bounds__(256)
void segend_kernel(const f4* __restrict__ x4,
                   const int* __restrict__ pos,
                   const float* __restrict__ dec,
                   const int* __restrict__ ci_tile,
                   f4* __restrict__ ez4,
                   float* __restrict__ Aseg) {
    const int blk = blockIdx.x;          // b*NTILE_ + k
    const int b = blk >> 7;              // NTILE_ = 128
    const int k = blk & (NTILE_ - 1);
    const int t = threadIdx.x;

    const int mlo = (k == 0) ? 0 : ci_tile[b * NTILE_ + k] + 1;
    const int mhi = (k == NTILE_ - 1) ? (M_ - 1) : ci_tile[b * NTILE_ + k + 1];
    const int n = mhi - mlo + 1;         // 0..64

    __shared__ int   pl[TROWS_];
    __shared__ float dl[TROWS_];
    if (t < n) {
        pl[t] = pos[(size_t)b * M_ + mlo + t];
        dl[t] = dec[(size_t)b * M_ + mlo + t];
    }
    __syncthreads();

    f4 h = (f4)(0.0f);
    float A = 1.0f;
    if (n > 0) {
        const f4* xrow = x4 + (size_t)b * L_ * D4_;
        for (int g = 0; g < n; g += 8) {
            f4    xv[8];
            float dd[8];
            #pragma unroll
            for (int j = 0; j < 8; j++) {
                const int mm = g + j;
                const int mc = (mm < n) ? mm : 0;
                dd[j] = (mm < n) ? dl[mc] : 1.0f;
                xv[j] = xrow[(size_t)pl[mc] * D4_ + t];
            }
            #pragma unroll
            for (int j = 0; j < 8; j++) {
                h = dd[j] * h + (1.0f - dd[j]) * xv[j];
                A *= dd[j];
            }
        }
    }
    ez4[(size_t)blk * D4_ + t] = h;
    if (t == 0) Aseg[blk] = A;
}

// ---------------- kernel 3: carry propagation across tiles + new_state ------
// grid (B, 16), block 64: scalar channel per thread (8192 parallel chains).
// hinit[b][k] = ema state ENTERING tile k (c_0 = state). ez prefetched in
// batches of 8 so the serial FMA chain stalls once per 8 steps.
__global__ __launch_bounds__(64)
void combine_kernel(const float* __restrict__ ez,
                    const float* __restrict__ Aseg,
                    const float* __restrict__ state,
                    float* __restrict__ hinit,
                    float* __restrict__ newstate) {
    const int b = blockIdx.x;
    const int ch = blockIdx.y * 64 + threadIdx.x;   // scalar channel 0..1023
    __shared__ float Al[NTILE_];
    for (int i = threadIdx.x; i < NTILE_; i += 64) Al[i] = Aseg[b * NTILE_ + i];
    __syncthreads();

    float c = state[(size_t)b * D_ + ch];
    for (int s0 = 0; s0 < NTILE_; s0 += 8) {
        float e[8];
        #pragma unroll
        for (int j = 0; j < 8; j++)
            e[j] = ez[((size_t)b * NTILE_ + s0 + j) * D_ + ch];
        #pragma unroll
        for (int j = 0; j < 8; j++) {
            hinit[((size_t)b * NTILE_ + s0 + j) * D_ + ch] = c;
            c = fmaf(Al[s0 + j], c, e[j]);
        }
    }
    newstate[(size_t)b * D_ + ch] = c;   // counts == M guaranteed
}

// ---------------- kernel 4: PURE-STREAM fused scan + scatter ----------------
// One block (256 threads) per (b, 64-row tile). h is seeded directly from
// hinit[b][k] (one 16B load — no prologue chain). Fixed 64-row NT pipeline;
// `live` mask handles the ci<0 prefix; ADV advances h at chunk boundaries
// with double-prefetched x gathers.
__global__ __launch_bounds__(256)
void fused_kernel(const f4* __restrict__ x4,
                  const f4* __restrict__ res4,
                  const int* __restrict__ pos,
                  const float* __restrict__ dec,
                  const int* __restrict__ ci_tile,
                  const f4* __restrict__ hinit4,
                  f4* __restrict__ out4) {
    const int blk = blockIdx.x;          // b*NTILE_ + k
    const int b = blk >> 7;              // NTILE_ = 128
    const int k = blk & (NTILE_ - 1);
    const int t = threadIdx.x;
    const int l0 = k * TROWS_;

    const int m0 = (k == 0) ? -1 : ci_tile[b * NTILE_ + k];

    // boundary list for this tile: chunks m0+1 .. m0+TROWS_+1 (sentinel-padded)
    __shared__ int   pl[TROWS_ + 2];
    __shared__ float dl[TROWS_ + 2];
    if (t < TROWS_ + 2) {
        const int mm = m0 + 1 + t;
        if (mm < M_) {
            pl[t] = pos[(size_t)b * M_ + mm];
            dl[t] = dec[(size_t)b * M_ + mm];
        } else {
            pl[t] = L_;                  // sentinel: never matches a row
            dl[t] = 1.0f;
        }
    }
    __syncthreads();

    const f4* xrow = x4 + (size_t)b * L_ * D4_;

    f4 h = hinit4[(size_t)blk * D4_ + t];   // state entering this tile
    float live = (m0 >= 0) ? 1.0f : 0.0f;

    const f4* resrow = res4 + (size_t)b * L_ * D4_;
    f4*       outrow = out4 + (size_t)b * L_ * D4_;

    int mi = 0;
    int nextb = pl[0];
    int a0 = (pl[0] < L_) ? pl[0] : 0;
    int a1 = (pl[1] < L_) ? pl[1] : 0;
    f4 xn  = xrow[(size_t)a0 * D4_ + t];
    f4 xn2 = xrow[(size_t)a1 * D4_ + t];
    int l = l0;

    #define ADV(K, HH, LV)                                                \
        if (l + (K) == nextb) {                                           \
            const float d_ = dl[mi];                                      \
            h = d_ * h + (1.0f - d_) * xn;                                \
            live = 1.0f;                                                  \
            xn = xn2;                                                     \
            ++mi;                                                         \
            nextb = pl[mi];                                               \
            const int nr_ = (pl[mi + 1] < L_) ? pl[mi + 1] : 0;           \
            xn2 = xrow[(size_t)nr_ * D4_ + t];                            \
        }                                                                 \
        HH = h; LV = live;

    f4 c0, c1, c2, c3;
    c0 = __builtin_nontemporal_load(resrow + (size_t)(l + 0) * D4_ + t);
    c1 = __builtin_nontemporal_load(resrow + (size_t)(l + 1) * D4_ + t);
    c2 = __builtin_nontemporal_load(resrow + (size_t)(l + 2) * D4_ + t);
    c3 = __builtin_nontemporal_load(resrow + (size_t)(l + 3) * D4_ + t);
    for (int g = 0; g < (TROWS_ / 4) - 1; ++g) {
        f4 n0 = __builtin_nontemporal_load(resrow + (size_t)(l + 4) * D4_ + t);
        f4 n1 = __builtin_nontemporal_load(resrow + (size_t)(l + 5) * D4_ + t);
        f4 n2 = __builtin_nontemporal_load(resrow + (size_t)(l + 6) * D4_ + t);
        f4 n3 = __builtin_nontemporal_load(resrow + (size_t)(l + 7) * D4_ + t);
        f4 h0, h1, h2, h3;
        float v0, v1, v2, v3;
        ADV(0, h0, v0); ADV(1, h1, v1); ADV(2, h2, v2); ADV(3, h3, v3);
        __builtin_nontemporal_store(c0 + v0 * h0, outrow + (size_t)(l + 0) * D4_ + t);
        __builtin_nontemporal_store(c1 + v1 * h1, outrow + (size_t)(l + 1) * D4_ + t);
        __builtin_nontemporal_store(c2 + v2 * h2, outrow + (size_t)(l + 2) * D4_ + t);
        __builtin_nontemporal_store(c3 + v3 * h3, outrow + (size_t)(l + 3) * D4_ + t);
        c0 = n0; c1 = n1; c2 = n2; c3 = n3;
        l += 4;
    }
    {
        f4 h0, h1, h2, h3;
        float v0, v1, v2, v3;
        ADV(0, h0, v0); ADV(1, h1, v1); ADV(2, h2, v2); ADV(3, h3, v3);
        __builtin_nontemporal_store(c0 + v0 * h0, outrow + (size_t)(l + 0) * D4_ + t);
        __builtin_nontemporal_store(c1 + v1 * h1, outrow + (size_t)(l + 1) * D4_ + t);
        __builtin_nontemporal_store(c2 + v2 * h2, outrow + (size_t)(l + 2) * D4_ + t);
        __builtin_nontemporal_store(c3 + v3 * h3, outrow + (size_t)(l + 3) * D4_ + t);
    }
    #undef ADV
}

extern "C" void kernel_launch(void* const* d_in, const int* in_sizes, int n_in,
                              void* d_out, int out_size, void* d_ws, size_t ws_size,
                              hipStream_t stream) {
    const float* x        = (const float*)d_in[0];
    const float* residual = (const float*)d_in[1];
    const float* prob     = (const float*)d_in[2];
    const void*  mask     = d_in[3];
    const float* state    = (const float*)d_in[4];

    float* out       = (float*)d_out;                       // (B,L,D)
    float* new_state = out + (size_t)B_ * L_ * D_;          // (B,D)

    if (ws_size < WS_TOTAL) return;  // fail loudly (zeros) rather than corrupt

    char* ws = (char*)d_ws;
    int*   pos     = (int*)  (ws + OFF_POS);
    float* dec     = (float*)(ws + OFF_DEC);
    float* Aseg    = (float*)(ws + OFF_A);
    int*   ci_tile = (int*)  (ws + OFF_CIT);
    float* ez      = (float*)(ws + OFF_EZ);
    float* hinit   = (float*)(ws + OFF_HINIT);

    compact_kernel<<<B_, 1024, 0, stream>>>(mask, prob, pos, dec, ci_tile);

    segend_kernel<<<B_ * NTILE_, 256, 0, stream>>>(
        (const f4*)x, pos, dec, ci_tile, (f4*)ez, Aseg);

    combine_kernel<<<dim3(B_, 16), 64, 0, stream>>>(
        ez, Aseg, state, hinit, new_state);

    fused_kernel<<<B_ * NTILE_, 256, 0, stream>>>(
        (const f4*)x, (const f4*)residual, pos, dec, ci_tile,
        (const f4*)hinit, (f4*)out);
}